// Round 7
// baseline (502.141 us; speedup 1.0000x reference)
//
#include <hip/hip_runtime.h>
#include <hip/hip_bf16.h>

// Problem constants
constexpr int Bb = 8, Nn = 4096, Ss = 1024;
constexpr int D1 = 128, D2 = 256, KIN = 384, OC = 256;
constexpr int L = Bb * Nn;             // 32768 rows
constexpr float BN_EPS = 1e-5f;

typedef __attribute__((ext_vector_type(4))) float floatx4;
typedef __attribute__((ext_vector_type(8))) __bf16 bf16x8;

#define DEV __device__ __forceinline__

DEV float bf2f(unsigned short u) {
    union { unsigned int i; float f; } v; v.i = ((unsigned int)u) << 16; return v.f;
}
DEV unsigned short f2bf(float f) {
    union { float f; unsigned int i; } v; v.f = f;
    unsigned int x = v.i;
    return (unsigned short)((x + 0x7FFFu + ((x >> 16) & 1u)) >> 16);  // RNE
}
// Fast tanh-form gelu: x*sigmoid(2u), u = sqrt(2/pi)*(x+0.044715x^3).
DEV float gelu_f(float x) {
    float u = x * (0.7978845608f + 0.0356774081f * x * x);
    float t = __expf(-2.0f * u);
    return x * __builtin_amdgcn_rcpf(1.0f + t);
}

// Per-block dtype probe (f32 low-halves are mantissa junk; bf16 pairs are sane).
DEV bool probe_isf(const unsigned int* __restrict__ w, int tid) {
    unsigned int lo = w[tid & 63] & 0xFFFFu;
    int e = (int)((lo >> 7) & 0xFF);
    unsigned long long m = __ballot(e >= 100 && e <= 144);
    return __popcll(m) < 48;
}

// Branchless merge of two sorted (asc) top-3 lists; pref=true -> ties keep "a".
DEV void merge3(float& d0, float& d1, float& d2, int& i0, int& i1, int& i2,
                float e0, float e1, float e2, int j0, int j1, int j2, bool pref) {
    float a0 = d0, a1 = d1, a2 = d2; int x0 = i0, x1 = i1, x2 = i2;
    float b0 = e0, b1 = e1;          int y0 = j0, y1 = j1;
    bool t = pref ? (a0 <= b0) : (a0 < b0);
    d0 = t ? a0 : b0; i0 = t ? x0 : y0;
    a0 = t ? a1 : a0; x0 = t ? x1 : x0;
    a1 = t ? a2 : a1; x1 = t ? x2 : x1;
    b0 = t ? b0 : b1; y0 = t ? y0 : y1;
    b1 = t ? b1 : e2; y1 = t ? y1 : j2;
    t = pref ? (a0 <= b0) : (a0 < b0);
    d1 = t ? a0 : b0; i1 = t ? x0 : y0;
    a0 = t ? a1 : a0; x0 = t ? x1 : x0;
    b0 = t ? b0 : b1; y0 = t ? y0 : y1;
    t = pref ? (a0 <= b0) : (a0 < b0);
    d2 = t ? a0 : b0; i2 = t ? x0 : y0;
}

// ---------------- launch 1: zero-stats | prep-weights (linear bf16) | 3-NN ----------------
__global__ __launch_bounds__(256) void k_front(const void* __restrict__ xyz1_,
                                               const void* __restrict__ xyz2_,
                                               const void* __restrict__ w0_,
                                               const void* __restrict__ w1_,
                                               const void* __restrict__ w2_,
                                               unsigned short* __restrict__ Wdst,
                                               float* __restrict__ stats,
                                               int* __restrict__ dflag,
                                               int* __restrict__ nn_idx,
                                               float* __restrict__ nn_w) {
    int tid = threadIdx.x;
    int bid = blockIdx.x;
    bool isf = probe_isf((const unsigned int*)xyz1_, tid);

    if (bid < 6) {
        stats[bid * 256 + tid] = 0.0f;
        if (bid == 0 && tid == 0) *dflag = isf ? 1 : 0;
        return;
    }
    if (bid < 902) {
        int i = (bid - 6) * 256 + tid;
        const void* src; int off;
        if (i < 98304)       { src = w0_; off = i; }
        else if (i < 163840) { src = w1_; off = i - 98304; }
        else                 { src = w2_; off = i - 163840; }
        Wdst[i] = isf ? f2bf(((const float*)src)[off]) : ((const unsigned short*)src)[off];
        return;
    }

    __shared__ alignas(16) float s4[Ss * 4 + 32];
    int bn0 = (bid - 902) * 32;
    int b = bn0 >> 12;

    if (isf) {
        const float* p2 = (const float*)xyz2_ + (size_t)b * Ss * 3;
        for (int i = tid; i < Ss * 3; i += 256) {
            int s = i / 3, k = i - s * 3;
            s4[s * 4 + k + ((s >> 7) << 2)] = p2[i];
        }
    } else {
        const unsigned short* p2 = (const unsigned short*)xyz2_ + (size_t)b * Ss * 3;
        for (int i = tid; i < Ss * 3; i += 256) {
            int s = i / 3, k = i - s * 3;
            s4[s * 4 + k + ((s >> 7) << 2)] = bf2f(p2[i]);
        }
    }
    __syncthreads();
    for (int s = tid; s < Ss; s += 256) {
        int a = s * 4 + ((s >> 7) << 2);
        float x = s4[a], y = s4[a + 1], z = s4[a + 2];
        s4[a + 3] = x * x + y * y + z * z;
    }
    __syncthreads();

    int part = tid & 7;
    int bn = bn0 + (tid >> 3);
    float x1, y1, z1;
    if (isf) {
        const float* p1 = (const float*)xyz1_ + (size_t)bn * 3;
        x1 = p1[0]; y1 = p1[1]; z1 = p1[2];
    } else {
        const unsigned short* p1 = (const unsigned short*)xyz1_ + (size_t)bn * 3;
        x1 = bf2f(p1[0]); y1 = bf2f(p1[1]); z1 = bf2f(p1[2]);
    }
    float n1 = x1 * x1 + y1 * y1 + z1 * z1;

    float d0 = 3.4e38f, d1 = 3.4e38f, d2 = 3.4e38f;
    int i0 = 0, i1 = 0, i2 = 0;
    const float* sp = &s4[part * 516];
#pragma unroll 4
    for (int j = 0; j < 128; ++j) {
        float4 qv = *(const float4*)(sp + j * 4);
        float d = n1 + qv.w - 2.0f * (x1 * qv.x + y1 * qv.y + z1 * qv.z);
        int s = part * 128 + j;
        bool c2 = d < d2, c1 = d < d1, c0 = d < d0;
        d2 = c1 ? d1 : (c2 ? d : d2); i2 = c1 ? i1 : (c2 ? s : i2);
        d1 = c0 ? d0 : (c1 ? d : d1); i1 = c0 ? i0 : (c1 ? s : i1);
        d0 = c0 ? d  : d0;            i0 = c0 ? s  : i0;
    }
#pragma unroll
    for (int m = 1; m <= 4; m <<= 1) {
        float e0 = __shfl_xor(d0, m, 64), e1 = __shfl_xor(d1, m, 64), e2 = __shfl_xor(d2, m, 64);
        int   j0 = __shfl_xor(i0, m, 64), j1 = __shfl_xor(i1, m, 64), j2 = __shfl_xor(i2, m, 64);
        bool pref = (part < (part ^ m));
        merge3(d0, d1, d2, i0, i1, i2, e0, e1, e2, j0, j1, j2, pref);
    }
    if (part == 0) {
        float r0 = 1.0f / (d0 + 1e-8f), r1 = 1.0f / (d1 + 1e-8f), r2 = 1.0f / (d2 + 1e-8f);
        float rs = 1.0f / (r0 + r1 + r2);
        nn_idx[bn * 3 + 0] = i0; nn_idx[bn * 3 + 1] = i1; nn_idx[bn * 3 + 2] = i2;
        nn_w[bn * 3 + 0] = r0 * rs; nn_w[bn * 3 + 1] = r1 * rs; nn_w[bn * 3 + 2] = r2 * rs;
    }
}

// ---------------- launch 2: k_interp -- materialize X = [p1|interp] linear bf16 ----------------
__global__ __launch_bounds__(256) void k_interp(const void* __restrict__ p1_,
                                                const void* __restrict__ p2_,
                                                const int* __restrict__ nn_idx,
                                                const float* __restrict__ nn_w,
                                                const int* __restrict__ dflag,
                                                unsigned short* __restrict__ X) {
    bool isf = (*dflag != 0);
    int i0_ = blockIdx.x * 256 + threadIdx.x;
    constexpr int GPR = KIN / 8;            // 48 groups of 8 per row
#pragma unroll
    for (int it = 0; it < 3; ++it) {
        int g = i0_ + it * 524288;          // 2048*256 threads, 3 iters = L*48 exactly
        int row = g / GPR, cg = g - row * GPR;
        union { uint4 v; unsigned short u[8]; } va;
        if (cg < 16) {
            int c0 = cg * 8;
            if (isf) {
                const float* p = (const float*)p1_ + (size_t)row * D1 + c0;
                float4 f0 = *(const float4*)p;
                float4 f1 = *(const float4*)(p + 4);
                va.u[0] = f2bf(f0.x); va.u[1] = f2bf(f0.y); va.u[2] = f2bf(f0.z); va.u[3] = f2bf(f0.w);
                va.u[4] = f2bf(f1.x); va.u[5] = f2bf(f1.y); va.u[6] = f2bf(f1.z); va.u[7] = f2bf(f1.w);
            } else {
                va.v = *(const uint4*)((const unsigned short*)p1_ + (size_t)row * D1 + c0);
            }
        } else {
            int c2 = (cg - 16) * 8;
            int b = row >> 12;
            int j0 = nn_idx[row * 3], j1 = nn_idx[row * 3 + 1], j2 = nn_idx[row * 3 + 2];
            float w0 = nn_w[row * 3], w1 = nn_w[row * 3 + 1], w2 = nn_w[row * 3 + 2];
            if (isf) {
                const float* base = (const float*)p2_;
                const float* r0 = base + ((size_t)(b * Ss + j0)) * D2 + c2;
                const float* r1 = base + ((size_t)(b * Ss + j1)) * D2 + c2;
                const float* r2 = base + ((size_t)(b * Ss + j2)) * D2 + c2;
#pragma unroll
                for (int h = 0; h < 2; ++h) {
                    float4 a0 = *(const float4*)(r0 + h * 4);
                    float4 a1 = *(const float4*)(r1 + h * 4);
                    float4 a2 = *(const float4*)(r2 + h * 4);
                    va.u[h * 4 + 0] = f2bf(w0 * a0.x + w1 * a1.x + w2 * a2.x);
                    va.u[h * 4 + 1] = f2bf(w0 * a0.y + w1 * a1.y + w2 * a2.y);
                    va.u[h * 4 + 2] = f2bf(w0 * a0.z + w1 * a1.z + w2 * a2.z);
                    va.u[h * 4 + 3] = f2bf(w0 * a0.w + w1 * a1.w + w2 * a2.w);
                }
            } else {
                const unsigned short* base = (const unsigned short*)p2_;
                uint4 v0 = *(const uint4*)(base + ((size_t)(b * Ss + j0)) * D2 + c2);
                uint4 v1 = *(const uint4*)(base + ((size_t)(b * Ss + j1)) * D2 + c2);
                uint4 v2 = *(const uint4*)(base + ((size_t)(b * Ss + j2)) * D2 + c2);
                const unsigned short* u0 = (const unsigned short*)&v0;
                const unsigned short* u1 = (const unsigned short*)&v1;
                const unsigned short* u2 = (const unsigned short*)&v2;
#pragma unroll
                for (int j = 0; j < 8; ++j)
                    va.u[j] = f2bf(w0 * bf2f(u0[j]) + w1 * bf2f(u1[j]) + w2 * bf2f(u2[j]));
            }
        }
        *(uint4*)&X[(size_t)row * KIN + cg * 8] = va.v;
    }
}

// ---------------- register GEMM: barrier-free, weight-stationary ----------------
// Each wave: 32 output cols x full K of W held in VGPR B-fragments (loaded once,
// L2-hot); streams 8 x 16-row A-chunks global->fragment->MFMA. No LDS, no
// __syncthreads -> compiler freely software-pipelines loads across chunks.
// Fragment addressing replicates the verified LDS mapping:
//   A/B lane l: row/col = base + (l&15), k = ks*32 + (l>>4)*8 + [0..7]
//   C   lane l: col = base + (l&15),  row = (l>>4)*4 + r
// Block covers 4 colgroups x same 128 rows (A rows L2-reused 4x in-block).
template <int K>
__global__ __launch_bounds__(256) void k_rgemm(const unsigned short* __restrict__ A,
                                               const unsigned short* __restrict__ W,
                                               unsigned short* __restrict__ Out,
                                               float* __restrict__ S1,
                                               float* __restrict__ S2) {
    constexpr int KS = K / 32;
    int tid = threadIdx.x;
    int wn = tid >> 6, lane = tid & 63, quad = lane >> 4, lr = lane & 15;
    int c0 = (((blockIdx.x & 1) << 2) | wn) * 32;   // colgroup: 8 of 32 cols
    int r0 = (blockIdx.x >> 1) * 128;               // 128 rows per wave

    bf16x8 bfrag[2][KS];
#pragma unroll
    for (int ni = 0; ni < 2; ++ni)
#pragma unroll
        for (int ks = 0; ks < KS; ++ks)
            bfrag[ni][ks] = *(const bf16x8*)&W[(size_t)(c0 + ni * 16 + lr) * K + ks * 32 + quad * 8];

    float p1[2] = {0.f, 0.f}, p2[2] = {0.f, 0.f};
#pragma unroll 2
    for (int ch = 0; ch < 8; ++ch) {
        const unsigned short* arow = A + (size_t)(r0 + ch * 16 + lr) * K + quad * 8;
        bf16x8 af[KS];
#pragma unroll
        for (int ks = 0; ks < KS; ++ks)
            af[ks] = *(const bf16x8*)(arow + ks * 32);
        floatx4 acc0 = (floatx4){0.f, 0.f, 0.f, 0.f};
        floatx4 acc1 = (floatx4){0.f, 0.f, 0.f, 0.f};
#pragma unroll
        for (int ks = 0; ks < KS; ++ks) {
            acc0 = __builtin_amdgcn_mfma_f32_16x16x32_bf16(af[ks], bfrag[0][ks], acc0, 0, 0, 0);
            acc1 = __builtin_amdgcn_mfma_f32_16x16x32_bf16(af[ks], bfrag[1][ks], acc1, 0, 0, 0);
        }
        int orow = r0 + ch * 16 + quad * 4;
#pragma unroll
        for (int r = 0; r < 4; ++r) {
            float v0 = acc0[r], v1 = acc1[r];
            Out[(size_t)(orow + r) * OC + c0 + lr]      = f2bf(v0);
            Out[(size_t)(orow + r) * OC + c0 + 16 + lr] = f2bf(v1);
            p1[0] += v0; p2[0] += v0 * v0;
            p1[1] += v1; p2[1] += v1 * v1;
        }
    }
    atomicAdd(&S1[c0 + lr],      p1[0]);
    atomicAdd(&S2[c0 + lr],      p2[0]);
    atomicAdd(&S1[c0 + 16 + lr], p1[1]);
    atomicAdd(&S2[c0 + 16 + lr], p2[1]);
}

// ---------------- k_act: Tout = gelu(bn(Tin)) elementwise, barrier-free stream ----------------
__global__ __launch_bounds__(256) void k_act(const unsigned short* __restrict__ Tin,
                                             unsigned short* __restrict__ Tout,
                                             const float* __restrict__ S1in,
                                             const float* __restrict__ S2in,
                                             const void* __restrict__ g_,
                                             const void* __restrict__ bt_,
                                             const int* __restrict__ dflag) {
    __shared__ float sCA[256], sCC[256];
    int tid = threadIdx.x;
    {
        float m = S1in[tid] * (1.0f / (float)L);
        float var = S2in[tid] * (1.0f / (float)L) - m * m;
        float g, bt;
        if (*dflag) { g = ((const float*)g_)[tid]; bt = ((const float*)bt_)[tid]; }
        else { g = bf2f(((const unsigned short*)g_)[tid]); bt = bf2f(((const unsigned short*)bt_)[tid]); }
        float a = g * rsqrtf(var + BN_EPS);
        sCA[tid] = a;
        sCC[tid] = bt - m * a;
    }
    __syncthreads();

    int idx = (blockIdx.x * 256 + tid) * 8;
    int col = idx & (OC - 1);
    union { uint4 v; unsigned short u[8]; } vi, vo;
    vi.v = *(const uint4*)(Tin + idx);
#pragma unroll
    for (int j = 0; j < 8; ++j)
        vo.u[j] = f2bf(gelu_f(sCA[col + j] * bf2f(vi.u[j]) + sCC[col + j]));
    *(uint4*)(Tout + idx) = vo.v;
}

// ---------------- k_final: out = gelu( bn2(t2) + gelu(bn0(t0)) ) ----------------
__global__ __launch_bounds__(256) void k_final(const unsigned short* __restrict__ t0,
                                               const unsigned short* __restrict__ t2,
                                               const float* __restrict__ S1_0, const float* __restrict__ S2_0,
                                               const float* __restrict__ S1_2, const float* __restrict__ S2_2,
                                               const void* __restrict__ g0_, const void* __restrict__ bt0_,
                                               const void* __restrict__ g2_, const void* __restrict__ bt2_,
                                               const int* __restrict__ dflag,
                                               void* __restrict__ out_) {
    __shared__ float sA0[256], sC0[256], sA2[256], sC2[256];
    int tid = threadIdx.x;
    bool isf = (*dflag != 0);
    {
        float m0 = S1_0[tid] * (1.0f / (float)L);
        float v0_ = S2_0[tid] * (1.0f / (float)L) - m0 * m0;
        float m2 = S1_2[tid] * (1.0f / (float)L);
        float v2_ = S2_2[tid] * (1.0f / (float)L) - m2 * m2;
        float g0, b0, g2, b2;
        if (isf) {
            g0 = ((const float*)g0_)[tid]; b0 = ((const float*)bt0_)[tid];
            g2 = ((const float*)g2_)[tid]; b2 = ((const float*)bt2_)[tid];
        } else {
            g0 = bf2f(((const unsigned short*)g0_)[tid]); b0 = bf2f(((const unsigned short*)bt0_)[tid]);
            g2 = bf2f(((const unsigned short*)g2_)[tid]); b2 = bf2f(((const unsigned short*)bt2_)[tid]);
        }
        float a0 = g0 * rsqrtf(v0_ + BN_EPS);
        float a2 = g2 * rsqrtf(v2_ + BN_EPS);
        sA0[tid] = a0; sC0[tid] = b0 - m0 * a0;
        sA2[tid] = a2; sC2[tid] = b2 - m2 * a2;
    }
    __syncthreads();

    int idx = (blockIdx.x * 256 + tid) * 8;
    int col = idx & (OC - 1);
    union { uint4 v; unsigned short u[8]; } v0, v2;
    v0.v = *(const uint4*)(t0 + idx);
    v2.v = *(const uint4*)(t2 + idx);
    float r[8];
#pragma unroll
    for (int j = 0; j < 8; ++j) {
        float x = gelu_f(sA0[col + j] * bf2f(v0.u[j]) + sC0[col + j]);
        float y = sA2[col + j] * bf2f(v2.u[j]) + sC2[col + j];
        r[j] = gelu_f(x + y);
    }
    if (isf) {
        float* o = (float*)out_ + idx;
        float4 lo = {r[0], r[1], r[2], r[3]};
        float4 hi = {r[4], r[5], r[6], r[7]};
        *(float4*)o = lo;
        *(float4*)(o + 4) = hi;
    } else {
        union { uint4 v; unsigned short u[8]; } vo;
#pragma unroll
        for (int j = 0; j < 8; ++j) vo.u[j] = f2bf(r[j]);
        *(uint4*)((unsigned short*)out_ + idx) = vo.v;
    }
}

extern "C" void kernel_launch(void* const* d_in, const int* in_sizes, int n_in,
                              void* d_out, int out_size, void* d_ws, size_t ws_size,
                              hipStream_t stream) {
    const void* xyz1    = d_in[0];
    const void* xyz2    = d_in[1];
    const void* points1 = d_in[2];
    const void* points2 = d_in[3];
    const void* W_fuse  = d_in[4];
    const void* g_fuse  = d_in[6];
    const void* bt_fuse = d_in[7];
    const void* W1      = d_in[8];
    const void* g1      = d_in[10];
    const void* bt1     = d_in[11];
    const void* W2      = d_in[12];
    const void* g2      = d_in[14];
    const void* bt2     = d_in[15];

    char* ws = (char*)d_ws;
    unsigned short* t0 = (unsigned short*)ws;                 // 16.8 MB raw GEMM1 out
    unsigned short* t2 = (unsigned short*)(ws + 16777216);    // 16.8 MB raw GEMM3 out
    unsigned short* ta = (unsigned short*)(ws + 33554432);    // 16.8 MB activated (t0a then t1a)
    unsigned short* X  = (unsigned short*)d_out;              // 25.2 MB scratch (dead after GEMM1)
    unsigned short* t1 = (unsigned short*)d_out;              // 16.8 MB raw GEMM2 out (overwrites dead X)
    int*   nn_idx = (int*)(ws + 50331648);
    float* nn_w   = (float*)(ws + 50724864);
    float* stats  = (float*)(ws + 51118080);
    int*   dflag  = (int*)(ws + 51124224);
    unsigned short* Wbf = (unsigned short*)(ws + 51126272);   // Wf | W1 | W2 linear bf16

    float *S1_0 = stats,        *S2_0 = stats + 256;
    float *S1_1 = stats + 512,  *S2_1 = stats + 768;
    float *S1_2 = stats + 1024, *S2_2 = stats + 1280;

    // 1: zero-stats + weight prep (linear bf16) + 3-NN
    k_front<<<1926, 256, 0, stream>>>(xyz1, xyz2, W_fuse, W1, W2, Wbf, stats, dflag, nn_idx, nn_w);
    // 2: materialize X (linear bf16)
    k_interp<<<2048, 256, 0, stream>>>(points1, points2, nn_idx, nn_w, dflag, X);
    // 3: GEMM1 (X -> t0, stats0), barrier-free register GEMM
    k_rgemm<KIN><<<512, 256, 0, stream>>>(X, Wbf, t0, S1_0, S2_0);
    // 4: act1: ta = gelu(bn0(t0))
    k_act<<<L * OC / (256 * 8), 256, 0, stream>>>(t0, ta, S1_0, S2_0, g_fuse, bt_fuse, dflag);
    // 5: GEMM2 (ta -> t1, stats1)
    k_rgemm<OC><<<512, 256, 0, stream>>>(ta, Wbf + 98304, t1, S1_1, S2_1);
    // 6: act2: ta = gelu(bn1(t1))   (reuses ta; t0a dead)
    k_act<<<L * OC / (256 * 8), 256, 0, stream>>>(t1, ta, S1_1, S2_1, g1, bt1, dflag);
    // 7: GEMM3 (ta -> t2, stats2)
    k_rgemm<OC><<<512, 256, 0, stream>>>(ta, Wbf + 163840, t2, S1_2, S2_2);
    // 8: final: out = gelu(bn2(t2) + gelu(bn0(t0)))
    k_final<<<L * OC / (256 * 8), 256, 0, stream>>>(t0, t2, S1_0, S2_0, S1_2, S2_2,
                                                    g_fuse, bt_fuse, g2, bt2, dflag, d_out);
}

// Round 9
// 265.650 us; speedup vs baseline: 1.8902x; 1.8902x over previous
//
#include <hip/hip_runtime.h>
#include <hip/hip_bf16.h>

// Problem constants
constexpr int Bb = 8, Nn = 4096, Ss = 1024;
constexpr int D1 = 128, D2 = 256, KIN = 384, OC = 256;
constexpr int L = Bb * Nn;             // 32768 rows
constexpr float BN_EPS = 1e-5f;

typedef __attribute__((ext_vector_type(4))) float floatx4;
typedef __attribute__((ext_vector_type(8))) __bf16 bf16x8;

#define DEV __device__ __forceinline__

DEV float bf2f(unsigned short u) {
    union { unsigned int i; float f; } v; v.i = ((unsigned int)u) << 16; return v.f;
}
DEV unsigned short f2bf(float f) {
    union { float f; unsigned int i; } v; v.f = f;
    unsigned int x = v.i;
    return (unsigned short)((x + 0x7FFFu + ((x >> 16) & 1u)) >> 16);  // RNE
}
// Fast tanh-form gelu: x*sigmoid(2u), u = sqrt(2/pi)*(x+0.044715x^3).
DEV float gelu_f(float x) {
    float u = x * (0.7978845608f + 0.0356774081f * x * x);
    float t = __expf(-2.0f * u);
    return x * __builtin_amdgcn_rcpf(1.0f + t);
}

// Per-block dtype probe (f32 low-halves are mantissa junk; bf16 pairs are sane).
DEV bool probe_isf(const unsigned int* __restrict__ w, int tid) {
    unsigned int lo = w[tid & 63] & 0xFFFFu;
    int e = (int)((lo >> 7) & 0xFF);
    unsigned long long m = __ballot(e >= 100 && e <= 144);
    return __popcll(m) < 48;
}

// Pre-swizzle permutation (W and X/ta share it): within each 64-col chunk,
// col-group cg of row r is stored at group (cg ^ (r&7)). GEMM stages linearly
// via global_load_lds; swizzled ds_read fragment indexing recovers the data.
template <int K> DEV int permoff(int off) {
    int row = off / K, rr = off - row * K;
    int cg_ = (rr >> 3) & 7;
    return row * K + (rr & ~63) + (((cg_ ^ (row & 7)) << 3)) + (rr & 7);
}

// Branchless merge of two sorted (asc) top-3 lists; pref=true -> ties keep "a".
DEV void merge3(float& d0, float& d1, float& d2, int& i0, int& i1, int& i2,
                float e0, float e1, float e2, int j0, int j1, int j2, bool pref) {
    float a0 = d0, a1 = d1, a2 = d2; int x0 = i0, x1 = i1, x2 = i2;
    float b0 = e0, b1 = e1;          int y0 = j0, y1 = j1;
    bool t = pref ? (a0 <= b0) : (a0 < b0);
    d0 = t ? a0 : b0; i0 = t ? x0 : y0;
    a0 = t ? a1 : a0; x0 = t ? x1 : x0;
    a1 = t ? a2 : a1; x1 = t ? x2 : x1;
    b0 = t ? b0 : b1; y0 = t ? y0 : y1;
    b1 = t ? b1 : e2; y1 = t ? y1 : j2;
    t = pref ? (a0 <= b0) : (a0 < b0);
    d1 = t ? a0 : b0; i1 = t ? x0 : y0;
    a0 = t ? a1 : a0; x0 = t ? x1 : x0;
    b0 = t ? b0 : b1; y0 = t ? y0 : y1;
    t = pref ? (a0 <= b0) : (a0 < b0);
    d2 = t ? a0 : b0; i2 = t ? x0 : y0;
}

// ---------------- launch 1: zero-stats | prep-weights (pre-swizzled bf16) | 3-NN ----------------
__global__ __launch_bounds__(256) void k_front(const void* __restrict__ xyz1_,
                                               const void* __restrict__ xyz2_,
                                               const void* __restrict__ w0_,
                                               const void* __restrict__ w1_,
                                               const void* __restrict__ w2_,
                                               unsigned short* __restrict__ Wdst,
                                               float* __restrict__ stats,
                                               int* __restrict__ dflag,
                                               int* __restrict__ nn_idx,
                                               float* __restrict__ nn_w) {
    int tid = threadIdx.x;
    int bid = blockIdx.x;
    bool isf = probe_isf((const unsigned int*)xyz1_, tid);

    if (bid < 6) {
        stats[bid * 256 + tid] = 0.0f;
        if (bid == 0 && tid == 0) *dflag = isf ? 1 : 0;
        return;
    }
    if (bid < 902) {
        int i = (bid - 6) * 256 + tid;
        const void* src; int off;
        if (i < 98304)       { src = w0_; off = permoff<384>(i); }
        else if (i < 163840) { src = w1_; off = permoff<256>(i - 98304); }
        else                 { src = w2_; off = permoff<256>(i - 163840); }
        Wdst[i] = isf ? f2bf(((const float*)src)[off]) : ((const unsigned short*)src)[off];
        return;
    }

    __shared__ alignas(16) float s4[Ss * 4 + 32];
    int bn0 = (bid - 902) * 32;
    int b = bn0 >> 12;

    if (isf) {
        const float* p2 = (const float*)xyz2_ + (size_t)b * Ss * 3;
        for (int i = tid; i < Ss * 3; i += 256) {
            int s = i / 3, k = i - s * 3;
            s4[s * 4 + k + ((s >> 7) << 2)] = p2[i];
        }
    } else {
        const unsigned short* p2 = (const unsigned short*)xyz2_ + (size_t)b * Ss * 3;
        for (int i = tid; i < Ss * 3; i += 256) {
            int s = i / 3, k = i - s * 3;
            s4[s * 4 + k + ((s >> 7) << 2)] = bf2f(p2[i]);
        }
    }
    __syncthreads();
    for (int s = tid; s < Ss; s += 256) {
        int a = s * 4 + ((s >> 7) << 2);
        float x = s4[a], y = s4[a + 1], z = s4[a + 2];
        s4[a + 3] = x * x + y * y + z * z;
    }
    __syncthreads();

    int part = tid & 7;
    int bn = bn0 + (tid >> 3);
    float x1, y1, z1;
    if (isf) {
        const float* p1 = (const float*)xyz1_ + (size_t)bn * 3;
        x1 = p1[0]; y1 = p1[1]; z1 = p1[2];
    } else {
        const unsigned short* p1 = (const unsigned short*)xyz1_ + (size_t)bn * 3;
        x1 = bf2f(p1[0]); y1 = bf2f(p1[1]); z1 = bf2f(p1[2]);
    }
    float n1 = x1 * x1 + y1 * y1 + z1 * z1;

    float d0 = 3.4e38f, d1 = 3.4e38f, d2 = 3.4e38f;
    int i0 = 0, i1 = 0, i2 = 0;
    const float* sp = &s4[part * 516];
#pragma unroll 4
    for (int j = 0; j < 128; ++j) {
        float4 qv = *(const float4*)(sp + j * 4);
        float d = n1 + qv.w - 2.0f * (x1 * qv.x + y1 * qv.y + z1 * qv.z);
        int s = part * 128 + j;
        bool c2 = d < d2, c1 = d < d1, c0 = d < d0;
        d2 = c1 ? d1 : (c2 ? d : d2); i2 = c1 ? i1 : (c2 ? s : i2);
        d1 = c0 ? d0 : (c1 ? d : d1); i1 = c0 ? i0 : (c1 ? s : i1);
        d0 = c0 ? d  : d0;            i0 = c0 ? s  : i0;
    }
#pragma unroll
    for (int m = 1; m <= 4; m <<= 1) {
        float e0 = __shfl_xor(d0, m, 64), e1 = __shfl_xor(d1, m, 64), e2 = __shfl_xor(d2, m, 64);
        int   j0 = __shfl_xor(i0, m, 64), j1 = __shfl_xor(i1, m, 64), j2 = __shfl_xor(i2, m, 64);
        bool pref = (part < (part ^ m));
        merge3(d0, d1, d2, i0, i1, i2, e0, e1, e2, j0, j1, j2, pref);
    }
    if (part == 0) {
        float r0 = 1.0f / (d0 + 1e-8f), r1 = 1.0f / (d1 + 1e-8f), r2 = 1.0f / (d2 + 1e-8f);
        float rs = 1.0f / (r0 + r1 + r2);
        nn_idx[bn * 3 + 0] = i0; nn_idx[bn * 3 + 1] = i1; nn_idx[bn * 3 + 2] = i2;
        nn_w[bn * 3 + 0] = r0 * rs; nn_w[bn * 3 + 1] = r1 * rs; nn_w[bn * 3 + 2] = r2 * rs;
    }
}

// ---------------- launch 2: k_interp -- X = [p1|interp], PRE-SWIZZLED bf16 ----------------
__global__ __launch_bounds__(256) void k_interp(const void* __restrict__ p1_,
                                                const void* __restrict__ p2_,
                                                const int* __restrict__ nn_idx,
                                                const float* __restrict__ nn_w,
                                                const int* __restrict__ dflag,
                                                unsigned short* __restrict__ X) {
    bool isf = (*dflag != 0);
    int i0_ = blockIdx.x * 256 + threadIdx.x;
    constexpr int GPR = KIN / 8;            // 48 groups of 8 per row
#pragma unroll
    for (int it = 0; it < 3; ++it) {
        int g = i0_ + it * 524288;          // 2048*256 threads, 3 iters = L*48 exactly
        int row = g / GPR, cg = g - row * GPR;
        int chunk = cg >> 3, cgc = cg & 7;
        union { uint4 v; unsigned short u[8]; } va;
        if (cg < 16) {
            int c0 = cg * 8;
            if (isf) {
                const float* p = (const float*)p1_ + (size_t)row * D1 + c0;
                float4 f0 = *(const float4*)p;
                float4 f1 = *(const float4*)(p + 4);
                va.u[0] = f2bf(f0.x); va.u[1] = f2bf(f0.y); va.u[2] = f2bf(f0.z); va.u[3] = f2bf(f0.w);
                va.u[4] = f2bf(f1.x); va.u[5] = f2bf(f1.y); va.u[6] = f2bf(f1.z); va.u[7] = f2bf(f1.w);
            } else {
                va.v = *(const uint4*)((const unsigned short*)p1_ + (size_t)row * D1 + c0);
            }
        } else {
            int c2 = (cg - 16) * 8;
            int b = row >> 12;
            int j0 = nn_idx[row * 3], j1 = nn_idx[row * 3 + 1], j2 = nn_idx[row * 3 + 2];
            float w0 = nn_w[row * 3], w1 = nn_w[row * 3 + 1], w2 = nn_w[row * 3 + 2];
            if (isf) {
                const float* base = (const float*)p2_;
                const float* r0 = base + ((size_t)(b * Ss + j0)) * D2 + c2;
                const float* r1 = base + ((size_t)(b * Ss + j1)) * D2 + c2;
                const float* r2 = base + ((size_t)(b * Ss + j2)) * D2 + c2;
#pragma unroll
                for (int h = 0; h < 2; ++h) {
                    float4 a0 = *(const float4*)(r0 + h * 4);
                    float4 a1 = *(const float4*)(r1 + h * 4);
                    float4 a2 = *(const float4*)(r2 + h * 4);
                    va.u[h * 4 + 0] = f2bf(w0 * a0.x + w1 * a1.x + w2 * a2.x);
                    va.u[h * 4 + 1] = f2bf(w0 * a0.y + w1 * a1.y + w2 * a2.y);
                    va.u[h * 4 + 2] = f2bf(w0 * a0.z + w1 * a1.z + w2 * a2.z);
                    va.u[h * 4 + 3] = f2bf(w0 * a0.w + w1 * a1.w + w2 * a2.w);
                }
            } else {
                const unsigned short* base = (const unsigned short*)p2_;
                uint4 v0 = *(const uint4*)(base + ((size_t)(b * Ss + j0)) * D2 + c2);
                uint4 v1 = *(const uint4*)(base + ((size_t)(b * Ss + j1)) * D2 + c2);
                uint4 v2 = *(const uint4*)(base + ((size_t)(b * Ss + j2)) * D2 + c2);
                const unsigned short* u0 = (const unsigned short*)&v0;
                const unsigned short* u1 = (const unsigned short*)&v1;
                const unsigned short* u2 = (const unsigned short*)&v2;
#pragma unroll
                for (int j = 0; j < 8; ++j)
                    va.u[j] = f2bf(w0 * bf2f(u0[j]) + w1 * bf2f(u1[j]) + w2 * bf2f(u2[j]));
            }
        }
        *(uint4*)&X[(size_t)row * KIN + chunk * 64 + ((cgc ^ (row & 7)) << 3)] = va.v;
    }
}

// ---------------- pipelined GEMM: W panel in LDS ONCE, kc loop stages only A ----------------
// BM=64 rows, BN cols per block, 256 thr = 4 waves (2M x 2N). W pre-swizzled ->
// global_load_lds linear; A (X or ta) also pre-swizzled -> glds linear. Per kc:
// barrier, 2 glds (8KB A), barrier(drain), ds_read frags + MFMA. W staged in
// prologue (first kc's drain covers it).
template <int K, int BN>
__global__ __launch_bounds__(256) void k_pgemm(const unsigned short* __restrict__ A,
                                               const unsigned short* __restrict__ W,
                                               unsigned short* __restrict__ Out,
                                               float* __restrict__ S1,
                                               float* __restrict__ S2) {
    constexpr int NSPLIT = OC / BN;
    constexpr int NI = BN / 32;                 // B tiles per wave (wave covers BN/2)
    constexpr int WITERS = BN * K / (8 * 256);  // 16B-loads per thread for W panel
    constexpr int NKC = K / 64;

    __shared__ alignas(16) unsigned short Ws[BN * K];
    __shared__ alignas(16) unsigned short As[64 * 64];
    __shared__ float sS1[BN], sS2[BN];

    int tid = threadIdx.x;
    int n0 = (blockIdx.x % NSPLIT) * BN;
    int m0 = (blockIdx.x / NSPLIT) * 64;
    int wn = tid >> 6, lane = tid & 63, quad = lane >> 4, lr = lane & 15;
    int wm = wn >> 1, wc = wn & 1;

    // Prologue: stage full W panel (pre-swizzled rows, linear dest)
#pragma unroll
    for (int it = 0; it < WITERS; ++it) {
        int c = it * 4 + wn;
        int flat = c * 512 + lane * 8;
        int row = flat / K, col = flat % K;
        const unsigned short* src = W + (size_t)(n0 + row) * K + col;
        __builtin_amdgcn_global_load_lds(
            (const __attribute__((address_space(1))) void*)src,
            (__attribute__((address_space(3))) void*)&Ws[c * 512],
            16, 0, 0);
    }
    if (tid < BN) { sS1[tid] = 0.f; sS2[tid] = 0.f; }

    floatx4 acc[2][NI];
#pragma unroll
    for (int mi = 0; mi < 2; ++mi)
#pragma unroll
        for (int ni = 0; ni < NI; ++ni) acc[mi][ni] = (floatx4){0.f, 0.f, 0.f, 0.f};

    for (int kc = 0; kc < NKC; ++kc) {
        __syncthreads();                        // prev readers done -> safe to overwrite As
#pragma unroll
        for (int it = 0; it < 2; ++it) {
            int c = it * 4 + wn;
            int flat = c * 512 + lane * 8;
            int row = flat >> 6, col = flat & 63;
            const unsigned short* src = A + (size_t)(m0 + row) * K + kc * 64 + col;
            __builtin_amdgcn_global_load_lds(
                (const __attribute__((address_space(1))) void*)src,
                (__attribute__((address_space(3))) void*)&As[c * 512],
                16, 0, 0);
        }
        __syncthreads();                        // vmcnt(0) drain: A (and W, first iter) ready
#pragma unroll
        for (int ks8 = 0; ks8 < 2; ++ks8) {
            bf16x8 af[2], bf[NI];
#pragma unroll
            for (int mi = 0; mi < 2; ++mi) {
                int ra = wm * 32 + mi * 16 + lr;
                af[mi] = *(const bf16x8*)&As[ra * 64 + ((((ks8 << 2) + quad) ^ (ra & 7)) << 3)];
            }
#pragma unroll
            for (int ni = 0; ni < NI; ++ni) {
                int rb = wc * (BN / 2) + ni * 16 + lr;
                bf[ni] = *(const bf16x8*)&Ws[rb * K + kc * 64 + ((((ks8 << 2) + quad) ^ (rb & 7)) << 3)];
            }
#pragma unroll
            for (int mi = 0; mi < 2; ++mi)
#pragma unroll
                for (int ni = 0; ni < NI; ++ni)
                    acc[mi][ni] = __builtin_amdgcn_mfma_f32_16x16x32_bf16(af[mi], bf[ni], acc[mi][ni], 0, 0, 0);
        }
    }

    float p1a[NI], p2a[NI];
#pragma unroll
    for (int ni = 0; ni < NI; ++ni) { p1a[ni] = 0.f; p2a[ni] = 0.f; }
#pragma unroll
    for (int mi = 0; mi < 2; ++mi)
#pragma unroll
        for (int ni = 0; ni < NI; ++ni)
#pragma unroll
            for (int r = 0; r < 4; ++r) {
                float v = acc[mi][ni][r];
                int row = m0 + wm * 32 + mi * 16 + quad * 4 + r;
                int col = n0 + wc * (BN / 2) + ni * 16 + lr;
                Out[(size_t)row * OC + col] = f2bf(v);
                p1a[ni] += v; p2a[ni] += v * v;
            }
    __syncthreads();
#pragma unroll
    for (int ni = 0; ni < NI; ++ni) {
        atomicAdd(&sS1[wc * (BN / 2) + ni * 16 + lr], p1a[ni]);
        atomicAdd(&sS2[wc * (BN / 2) + ni * 16 + lr], p2a[ni]);
    }
    __syncthreads();
    if (tid < BN) {
        atomicAdd(&S1[n0 + tid], sS1[tid]);
        atomicAdd(&S2[n0 + tid], sS2[tid]);
    }
}

// ---------------- k_act: ta = gelu(bn(Tin)), PRE-SWIZZLED write ----------------
__global__ __launch_bounds__(256) void k_act(const unsigned short* __restrict__ Tin,
                                             unsigned short* __restrict__ Tout,
                                             const float* __restrict__ S1in,
                                             const float* __restrict__ S2in,
                                             const void* __restrict__ g_,
                                             const void* __restrict__ bt_,
                                             const int* __restrict__ dflag) {
    __shared__ float sCA[256], sCC[256];
    int tid = threadIdx.x;
    {
        float m = S1in[tid] * (1.0f / (float)L);
        float var = S2in[tid] * (1.0f / (float)L) - m * m;
        float g, bt;
        if (*dflag) { g = ((const float*)g_)[tid]; bt = ((const float*)bt_)[tid]; }
        else { g = bf2f(((const unsigned short*)g_)[tid]); bt = bf2f(((const unsigned short*)bt_)[tid]); }
        float a = g * rsqrtf(var + BN_EPS);
        sCA[tid] = a;
        sCC[tid] = bt - m * a;
    }
    __syncthreads();

    int idx = (blockIdx.x * 256 + tid) * 8;
    int row = idx >> 8;                  // OC=256 cols per row
    int cg = (idx & 255) >> 3;
    int col = idx & (OC - 1);
    union { uint4 v; unsigned short u[8]; } vi, vo;
    vi.v = *(const uint4*)(Tin + idx);
#pragma unroll
    for (int j = 0; j < 8; ++j)
        vo.u[j] = f2bf(gelu_f(sCA[col + j] * bf2f(vi.u[j]) + sCC[col + j]));
    int sg = (cg & 24) | ((cg & 7) ^ (row & 7));
    *(uint4*)(Tout + (size_t)row * OC + sg * 8) = vo.v;
}

// ---------------- k_final: out = gelu( bn2(t2) + gelu(bn0(t0)) ) ----------------
__global__ __launch_bounds__(256) void k_final(const unsigned short* __restrict__ t0,
                                               const unsigned short* __restrict__ t2,
                                               const float* __restrict__ S1_0, const float* __restrict__ S2_0,
                                               const float* __restrict__ S1_2, const float* __restrict__ S2_2,
                                               const void* __restrict__ g0_, const void* __restrict__ bt0_,
                                               const void* __restrict__ g2_, const void* __restrict__ bt2_,
                                               const int* __restrict__ dflag,
                                               void* __restrict__ out_) {
    __shared__ float sA0[256], sC0[256], sA2[256], sC2[256];
    int tid = threadIdx.x;
    bool isf = (*dflag != 0);
    {
        float m0 = S1_0[tid] * (1.0f / (float)L);
        float v0_ = S2_0[tid] * (1.0f / (float)L) - m0 * m0;
        float m2 = S1_2[tid] * (1.0f / (float)L);
        float v2_ = S2_2[tid] * (1.0f / (float)L) - m2 * m2;
        float g0, b0, g2, b2;
        if (isf) {
            g0 = ((const float*)g0_)[tid]; b0 = ((const float*)bt0_)[tid];
            g2 = ((const float*)g2_)[tid]; b2 = ((const float*)bt2_)[tid];
        } else {
            g0 = bf2f(((const unsigned short*)g0_)[tid]); b0 = bf2f(((const unsigned short*)bt0_)[tid]);
            g2 = bf2f(((const unsigned short*)g2_)[tid]); b2 = bf2f(((const unsigned short*)bt2_)[tid]);
        }
        float a0 = g0 * rsqrtf(v0_ + BN_EPS);
        float a2 = g2 * rsqrtf(v2_ + BN_EPS);
        sA0[tid] = a0; sC0[tid] = b0 - m0 * a0;
        sA2[tid] = a2; sC2[tid] = b2 - m2 * a2;
    }
    __syncthreads();

    int idx = (blockIdx.x * 256 + tid) * 8;
    int col = idx & (OC - 1);
    union { uint4 v; unsigned short u[8]; } v0, v2;
    v0.v = *(const uint4*)(t0 + idx);
    v2.v = *(const uint4*)(t2 + idx);
    float r[8];
#pragma unroll
    for (int j = 0; j < 8; ++j) {
        float x = gelu_f(sA0[col + j] * bf2f(v0.u[j]) + sC0[col + j]);
        float y = sA2[col + j] * bf2f(v2.u[j]) + sC2[col + j];
        r[j] = gelu_f(x + y);
    }
    if (isf) {
        float* o = (float*)out_ + idx;
        float4 lo = {r[0], r[1], r[2], r[3]};
        float4 hi = {r[4], r[5], r[6], r[7]};
        *(float4*)o = lo;
        *(float4*)(o + 4) = hi;
    } else {
        union { uint4 v; unsigned short u[8]; } vo;
#pragma unroll
        for (int j = 0; j < 8; ++j) vo.u[j] = f2bf(r[j]);
        *(uint4*)((unsigned short*)out_ + idx) = vo.v;
    }
}

extern "C" void kernel_launch(void* const* d_in, const int* in_sizes, int n_in,
                              void* d_out, int out_size, void* d_ws, size_t ws_size,
                              hipStream_t stream) {
    const void* xyz1    = d_in[0];
    const void* xyz2    = d_in[1];
    const void* points1 = d_in[2];
    const void* points2 = d_in[3];
    const void* W_fuse  = d_in[4];
    const void* g_fuse  = d_in[6];
    const void* bt_fuse = d_in[7];
    const void* W1      = d_in[8];
    const void* g1      = d_in[10];
    const void* bt1     = d_in[11];
    const void* W2      = d_in[12];
    const void* g2      = d_in[14];
    const void* bt2     = d_in[15];

    char* ws = (char*)d_ws;
    unsigned short* t0 = (unsigned short*)ws;                 // 16.8 MB raw GEMM1 out
    unsigned short* t2 = (unsigned short*)(ws + 16777216);    // 16.8 MB raw GEMM3 out
    unsigned short* ta = (unsigned short*)(ws + 33554432);    // 16.8 MB activated (pre-swizzled)
    unsigned short* X  = (unsigned short*)d_out;              // 25.2 MB pre-swizzled (dead after GEMM1)
    unsigned short* t1 = (unsigned short*)d_out;              // 16.8 MB raw GEMM2 out (overwrites dead X)
    int*   nn_idx = (int*)(ws + 50331648);
    float* nn_w   = (float*)(ws + 50724864);
    float* stats  = (float*)(ws + 51118080);
    int*   dflag  = (int*)(ws + 51124224);
    unsigned short* Wbf = (unsigned short*)(ws + 51126272);   // Wf | W1 | W2, PRE-SWIZZLED bf16

    float *S1_0 = stats,        *S2_0 = stats + 256;
    float *S1_1 = stats + 512,  *S2_1 = stats + 768;
    float *S1_2 = stats + 1024, *S2_2 = stats + 1280;

    // 1: zero-stats + weight prep (pre-swizzled) + 3-NN
    k_front<<<1926, 256, 0, stream>>>(xyz1, xyz2, W_fuse, W1, W2, Wbf, stats, dflag, nn_idx, nn_w);
    // 2: materialize X (pre-swizzled bf16)
    k_interp<<<2048, 256, 0, stream>>>(points1, points2, nn_idx, nn_w, dflag, X);
    // 3: GEMM1 (X -> t0, stats0): K=384, BN=64, grid 512x4
    k_pgemm<KIN, 64><<<(L / 64) * 4, 256, 0, stream>>>(X, Wbf, t0, S1_0, S2_0);
    // 4: act1: ta = gelu(bn0(t0)), pre-swizzled
    k_act<<<L * OC / (256 * 8), 256, 0, stream>>>(t0, ta, S1_0, S2_0, g_fuse, bt_fuse, dflag);
    // 5: GEMM2 (ta -> t1, stats1): K=256, BN=128, grid 512x2
    k_pgemm<OC, 128><<<(L / 64) * 2, 256, 0, stream>>>(ta, Wbf + 98304, t1, S1_1, S2_1);
    // 6: act2: ta = gelu(bn1(t1)), pre-swizzled
    k_act<<<L * OC / (256 * 8), 256, 0, stream>>>(t1, ta, S1_1, S2_1, g1, bt1, dflag);
    // 7: GEMM3 (ta -> t2, stats2)
    k_pgemm<OC, 128><<<(L / 64) * 2, 256, 0, stream>>>(ta, Wbf + 163840, t2, S1_2, S2_2);
    // 8: final: out = gelu(bn2(t2) + gelu(bn0(t0)))
    k_final<<<L * OC / (256 * 8), 256, 0, stream>>>(t0, t2, S1_0, S2_0, S1_2, S2_2,
                                                    g_fuse, bt_fuse, g2, bt2, dflag, d_out);
}

// Round 10
// 256.027 us; speedup vs baseline: 1.9613x; 1.0376x over previous
//
#include <hip/hip_runtime.h>
#include <hip/hip_bf16.h>

// Problem constants
constexpr int Bb = 8, Nn = 4096, Ss = 1024;
constexpr int D1 = 128, D2 = 256, KIN = 384, OC = 256;
constexpr int L = Bb * Nn;             // 32768 rows
constexpr float BN_EPS = 1e-5f;

typedef __attribute__((ext_vector_type(4))) float floatx4;
typedef __attribute__((ext_vector_type(8))) __bf16 bf16x8;

#define DEV __device__ __forceinline__

DEV float bf2f(unsigned short u) {
    union { unsigned int i; float f; } v; v.i = ((unsigned int)u) << 16; return v.f;
}
DEV unsigned short f2bf(float f) {
    union { float f; unsigned int i; } v; v.f = f;
    unsigned int x = v.i;
    return (unsigned short)((x + 0x7FFFu + ((x >> 16) & 1u)) >> 16);  // RNE
}
// Fast tanh-form gelu: x*sigmoid(2u), u = sqrt(2/pi)*(x+0.044715x^3).
DEV float gelu_f(float x) {
    float u = x * (0.7978845608f + 0.0356774081f * x * x);
    float t = __expf(-2.0f * u);
    return x * __builtin_amdgcn_rcpf(1.0f + t);
}

// Per-block dtype probe (f32 low-halves are mantissa junk; bf16 pairs are sane).
DEV bool probe_isf(const unsigned int* __restrict__ w, int tid) {
    unsigned int lo = w[tid & 63] & 0xFFFFu;
    int e = (int)((lo >> 7) & 0xFF);
    unsigned long long m = __ballot(e >= 100 && e <= 144);
    return __popcll(m) < 48;
}

// Pre-swizzle permutation (W and X share it): within each 64-col chunk,
// col-group cg of row r is stored at group (cg ^ (r&7)). GEMM stages linearly
// via global_load_lds; swizzled ds_read fragment indexing recovers the data.
template <int K> DEV int permoff(int off) {
    int row = off / K, rr = off - row * K;
    int cg_ = (rr >> 3) & 7;
    return row * K + (rr & ~63) + (((cg_ ^ (row & 7)) << 3)) + (rr & 7);
}

// Branchless merge of two sorted (asc) top-3 lists; pref=true -> ties keep "a".
DEV void merge3(float& d0, float& d1, float& d2, int& i0, int& i1, int& i2,
                float e0, float e1, float e2, int j0, int j1, int j2, bool pref) {
    float a0 = d0, a1 = d1, a2 = d2; int x0 = i0, x1 = i1, x2 = i2;
    float b0 = e0, b1 = e1;          int y0 = j0, y1 = j1;
    bool t = pref ? (a0 <= b0) : (a0 < b0);
    d0 = t ? a0 : b0; i0 = t ? x0 : y0;
    a0 = t ? a1 : a0; x0 = t ? x1 : x0;
    a1 = t ? a2 : a1; x1 = t ? x2 : x1;
    b0 = t ? b0 : b1; y0 = t ? y0 : y1;
    b1 = t ? b1 : e2; y1 = t ? y1 : j2;
    t = pref ? (a0 <= b0) : (a0 < b0);
    d1 = t ? a0 : b0; i1 = t ? x0 : y0;
    a0 = t ? a1 : a0; x0 = t ? x1 : x0;
    b0 = t ? b0 : b1; y0 = t ? y0 : y1;
    t = pref ? (a0 <= b0) : (a0 < b0);
    d2 = t ? a0 : b0; i2 = t ? x0 : y0;
}

// ---------------- launch 1: zero-stats | prep-weights (pre-swizzled bf16) | 3-NN ----------------
__global__ __launch_bounds__(256) void k_front(const void* __restrict__ xyz1_,
                                               const void* __restrict__ xyz2_,
                                               const void* __restrict__ w0_,
                                               const void* __restrict__ w1_,
                                               const void* __restrict__ w2_,
                                               unsigned short* __restrict__ Wdst,
                                               float* __restrict__ stats,
                                               int* __restrict__ dflag,
                                               int* __restrict__ nn_idx,
                                               float* __restrict__ nn_w) {
    int tid = threadIdx.x;
    int bid = blockIdx.x;
    bool isf = probe_isf((const unsigned int*)xyz1_, tid);

    if (bid < 6) {
        stats[bid * 256 + tid] = 0.0f;
        if (bid == 0 && tid == 0) *dflag = isf ? 1 : 0;
        return;
    }
    if (bid < 902) {
        int i = (bid - 6) * 256 + tid;
        const void* src; int off;
        if (i < 98304)       { src = w0_; off = permoff<384>(i); }
        else if (i < 163840) { src = w1_; off = permoff<256>(i - 98304); }
        else                 { src = w2_; off = permoff<256>(i - 163840); }
        Wdst[i] = isf ? f2bf(((const float*)src)[off]) : ((const unsigned short*)src)[off];
        return;
    }

    __shared__ alignas(16) float s4[Ss * 4 + 32];
    int bn0 = (bid - 902) * 32;
    int b = bn0 >> 12;

    if (isf) {
        const float* p2 = (const float*)xyz2_ + (size_t)b * Ss * 3;
        for (int i = tid; i < Ss * 3; i += 256) {
            int s = i / 3, k = i - s * 3;
            s4[s * 4 + k + ((s >> 7) << 2)] = p2[i];
        }
    } else {
        const unsigned short* p2 = (const unsigned short*)xyz2_ + (size_t)b * Ss * 3;
        for (int i = tid; i < Ss * 3; i += 256) {
            int s = i / 3, k = i - s * 3;
            s4[s * 4 + k + ((s >> 7) << 2)] = bf2f(p2[i]);
        }
    }
    __syncthreads();
    for (int s = tid; s < Ss; s += 256) {
        int a = s * 4 + ((s >> 7) << 2);
        float x = s4[a], y = s4[a + 1], z = s4[a + 2];
        s4[a + 3] = x * x + y * y + z * z;
    }
    __syncthreads();

    int part = tid & 7;
    int bn = bn0 + (tid >> 3);
    float x1, y1, z1;
    if (isf) {
        const float* p1 = (const float*)xyz1_ + (size_t)bn * 3;
        x1 = p1[0]; y1 = p1[1]; z1 = p1[2];
    } else {
        const unsigned short* p1 = (const unsigned short*)xyz1_ + (size_t)bn * 3;
        x1 = bf2f(p1[0]); y1 = bf2f(p1[1]); z1 = bf2f(p1[2]);
    }
    float n1 = x1 * x1 + y1 * y1 + z1 * z1;

    float d0 = 3.4e38f, d1 = 3.4e38f, d2 = 3.4e38f;
    int i0 = 0, i1 = 0, i2 = 0;
    const float* sp = &s4[part * 516];
#pragma unroll 4
    for (int j = 0; j < 128; ++j) {
        float4 qv = *(const float4*)(sp + j * 4);
        float d = n1 + qv.w - 2.0f * (x1 * qv.x + y1 * qv.y + z1 * qv.z);
        int s = part * 128 + j;
        bool c2 = d < d2, c1 = d < d1, c0 = d < d0;
        d2 = c1 ? d1 : (c2 ? d : d2); i2 = c1 ? i1 : (c2 ? s : i2);
        d1 = c0 ? d0 : (c1 ? d : d1); i1 = c0 ? i0 : (c1 ? s : i1);
        d0 = c0 ? d  : d0;            i0 = c0 ? s  : i0;
    }
#pragma unroll
    for (int m = 1; m <= 4; m <<= 1) {
        float e0 = __shfl_xor(d0, m, 64), e1 = __shfl_xor(d1, m, 64), e2 = __shfl_xor(d2, m, 64);
        int   j0 = __shfl_xor(i0, m, 64), j1 = __shfl_xor(i1, m, 64), j2 = __shfl_xor(i2, m, 64);
        bool pref = (part < (part ^ m));
        merge3(d0, d1, d2, i0, i1, i2, e0, e1, e2, j0, j1, j2, pref);
    }
    if (part == 0) {
        float r0 = 1.0f / (d0 + 1e-8f), r1 = 1.0f / (d1 + 1e-8f), r2 = 1.0f / (d2 + 1e-8f);
        float rs = 1.0f / (r0 + r1 + r2);
        nn_idx[bn * 3 + 0] = i0; nn_idx[bn * 3 + 1] = i1; nn_idx[bn * 3 + 2] = i2;
        nn_w[bn * 3 + 0] = r0 * rs; nn_w[bn * 3 + 1] = r1 * rs; nn_w[bn * 3 + 2] = r2 * rs;
    }
}

// ---------------- launch 2: k_interp -- X = [p1|interp], PRE-SWIZZLED bf16 ----------------
__global__ __launch_bounds__(256) void k_interp(const void* __restrict__ p1_,
                                                const void* __restrict__ p2_,
                                                const int* __restrict__ nn_idx,
                                                const float* __restrict__ nn_w,
                                                const int* __restrict__ dflag,
                                                unsigned short* __restrict__ X) {
    bool isf = (*dflag != 0);
    int i0_ = blockIdx.x * 256 + threadIdx.x;
    constexpr int GPR = KIN / 8;            // 48 groups of 8 per row
#pragma unroll
    for (int it = 0; it < 3; ++it) {
        int g = i0_ + it * 524288;          // 2048*256 threads, 3 iters = L*48 exactly
        int row = g / GPR, cg = g - row * GPR;
        int chunk = cg >> 3, cgc = cg & 7;
        union { uint4 v; unsigned short u[8]; } va;
        if (cg < 16) {
            int c0 = cg * 8;
            if (isf) {
                const float* p = (const float*)p1_ + (size_t)row * D1 + c0;
                float4 f0 = *(const float4*)p;
                float4 f1 = *(const float4*)(p + 4);
                va.u[0] = f2bf(f0.x); va.u[1] = f2bf(f0.y); va.u[2] = f2bf(f0.z); va.u[3] = f2bf(f0.w);
                va.u[4] = f2bf(f1.x); va.u[5] = f2bf(f1.y); va.u[6] = f2bf(f1.z); va.u[7] = f2bf(f1.w);
            } else {
                va.v = *(const uint4*)((const unsigned short*)p1_ + (size_t)row * D1 + c0);
            }
        } else {
            int c2 = (cg - 16) * 8;
            int b = row >> 12;
            int j0 = nn_idx[row * 3], j1 = nn_idx[row * 3 + 1], j2 = nn_idx[row * 3 + 2];
            float w0 = nn_w[row * 3], w1 = nn_w[row * 3 + 1], w2 = nn_w[row * 3 + 2];
            if (isf) {
                const float* base = (const float*)p2_;
                const float* r0 = base + ((size_t)(b * Ss + j0)) * D2 + c2;
                const float* r1 = base + ((size_t)(b * Ss + j1)) * D2 + c2;
                const float* r2 = base + ((size_t)(b * Ss + j2)) * D2 + c2;
#pragma unroll
                for (int h = 0; h < 2; ++h) {
                    float4 a0 = *(const float4*)(r0 + h * 4);
                    float4 a1 = *(const float4*)(r1 + h * 4);
                    float4 a2 = *(const float4*)(r2 + h * 4);
                    va.u[h * 4 + 0] = f2bf(w0 * a0.x + w1 * a1.x + w2 * a2.x);
                    va.u[h * 4 + 1] = f2bf(w0 * a0.y + w1 * a1.y + w2 * a2.y);
                    va.u[h * 4 + 2] = f2bf(w0 * a0.z + w1 * a1.z + w2 * a2.z);
                    va.u[h * 4 + 3] = f2bf(w0 * a0.w + w1 * a1.w + w2 * a2.w);
                }
            } else {
                const unsigned short* base = (const unsigned short*)p2_;
                uint4 v0 = *(const uint4*)(base + ((size_t)(b * Ss + j0)) * D2 + c2);
                uint4 v1 = *(const uint4*)(base + ((size_t)(b * Ss + j1)) * D2 + c2);
                uint4 v2 = *(const uint4*)(base + ((size_t)(b * Ss + j2)) * D2 + c2);
                const unsigned short* u0 = (const unsigned short*)&v0;
                const unsigned short* u1 = (const unsigned short*)&v1;
                const unsigned short* u2 = (const unsigned short*)&v2;
#pragma unroll
                for (int j = 0; j < 8; ++j)
                    va.u[j] = f2bf(w0 * bf2f(u0[j]) + w1 * bf2f(u1[j]) + w2 * bf2f(u2[j]));
            }
        }
        *(uint4*)&X[(size_t)row * KIN + chunk * 64 + ((cgc ^ (row & 7)) << 3)] = va.v;
    }
}

// ---------------- pipelined GEMM: W panel in LDS ONCE; optional fused BN+gelu on A ----------------
// BM=64 rows, BN cols per block, 256 thr = 4 waves (2M x 2N). W pre-swizzled ->
// global_load_lds linear (staged once in prologue). Per kc: barrier, stage A
// (glds if !ACT: A pre-swizzled; reg+transform+swizzled ds_write if ACT: A raw),
// barrier(drain), ds_read frags + MFMA.
template <int K, int BN, bool ACT>
__global__ __launch_bounds__(256) void k_pgemm(const unsigned short* __restrict__ A,
                                               const unsigned short* __restrict__ W,
                                               unsigned short* __restrict__ Out,
                                               float* __restrict__ S1,
                                               float* __restrict__ S2,
                                               const float* __restrict__ S1in,
                                               const float* __restrict__ S2in,
                                               const void* __restrict__ g_,
                                               const void* __restrict__ bt_,
                                               const int* __restrict__ dflag) {
    constexpr int NSPLIT = OC / BN;
    constexpr int NI = BN / 32;                 // B tiles per wave (wave covers BN/2)
    constexpr int WITERS = BN * K / (8 * 256);  // 16B-loads per thread for W panel
    constexpr int NKC = K / 64;

    __shared__ alignas(16) unsigned short Ws[BN * K];
    __shared__ alignas(16) unsigned short As[64 * 64];
    __shared__ float sS1[BN], sS2[BN];
    __shared__ float sCA[256], sCC[256];

    int tid = threadIdx.x;
    int n0 = (blockIdx.x % NSPLIT) * BN;
    int m0 = (blockIdx.x / NSPLIT) * 64;
    int wn = tid >> 6, lane = tid & 63, quad = lane >> 4, lr = lane & 15;
    int wm = wn >> 1, wc = wn & 1;

    // Prologue: stage full W panel (pre-swizzled rows, linear dest)
#pragma unroll
    for (int it = 0; it < WITERS; ++it) {
        int c = it * 4 + wn;
        int flat = c * 512 + lane * 8;
        int row = flat / K, col = flat % K;
        const unsigned short* src = W + (size_t)(n0 + row) * K + col;
        __builtin_amdgcn_global_load_lds(
            (const __attribute__((address_space(1))) void*)src,
            (__attribute__((address_space(3))) void*)&Ws[c * 512],
            16, 0, 0);
    }
    if constexpr (ACT) {
        float m = S1in[tid] * (1.0f / (float)L);
        float var = S2in[tid] * (1.0f / (float)L) - m * m;
        float g, bt;
        if (*dflag) { g = ((const float*)g_)[tid]; bt = ((const float*)bt_)[tid]; }
        else { g = bf2f(((const unsigned short*)g_)[tid]); bt = bf2f(((const unsigned short*)bt_)[tid]); }
        float a = g * rsqrtf(var + BN_EPS);
        sCA[tid] = a;
        sCC[tid] = bt - m * a;
    }
    if (tid < BN) { sS1[tid] = 0.f; sS2[tid] = 0.f; }

    floatx4 acc[2][NI];
#pragma unroll
    for (int mi = 0; mi < 2; ++mi)
#pragma unroll
        for (int ni = 0; ni < NI; ++ni) acc[mi][ni] = (floatx4){0.f, 0.f, 0.f, 0.f};

    for (int kc = 0; kc < NKC; ++kc) {
        __syncthreads();                        // kc=0: drains W glds + orders sCA writes
        if constexpr (!ACT) {
#pragma unroll
            for (int it = 0; it < 2; ++it) {
                int c = it * 4 + wn;
                int flat = c * 512 + lane * 8;
                int row = flat >> 6, col = flat & 63;
                const unsigned short* src = A + (size_t)(m0 + row) * K + kc * 64 + col;
                __builtin_amdgcn_global_load_lds(
                    (const __attribute__((address_space(1))) void*)src,
                    (__attribute__((address_space(3))) void*)&As[c * 512],
                    16, 0, 0);
            }
        } else {
#pragma unroll
            for (int it = 0; it < 2; ++it) {
                int idx = it * 256 + tid, row = idx >> 3, c8 = idx & 7;
                union { uint4 v; unsigned short u[8]; } va;
                va.v = *(const uint4*)(A + (size_t)(m0 + row) * K + kc * 64 + c8 * 8);
                int kb = kc * 64 + c8 * 8;
#pragma unroll
                for (int j = 0; j < 8; ++j) {
                    float f = bf2f(va.u[j]);
                    va.u[j] = f2bf(gelu_f(sCA[kb + j] * f + sCC[kb + j]));
                }
                *(uint4*)&As[row * 64 + ((c8 ^ (row & 7)) << 3)] = va.v;
            }
        }
        __syncthreads();                        // drain: As (and Ws, first iter) ready
#pragma unroll
        for (int ks8 = 0; ks8 < 2; ++ks8) {
            bf16x8 af[2], bf[NI];
#pragma unroll
            for (int mi = 0; mi < 2; ++mi) {
                int ra = wm * 32 + mi * 16 + lr;
                af[mi] = *(const bf16x8*)&As[ra * 64 + ((((ks8 << 2) + quad) ^ (ra & 7)) << 3)];
            }
#pragma unroll
            for (int ni = 0; ni < NI; ++ni) {
                int rb = wc * (BN / 2) + ni * 16 + lr;
                bf[ni] = *(const bf16x8*)&Ws[rb * K + kc * 64 + ((((ks8 << 2) + quad) ^ (rb & 7)) << 3)];
            }
#pragma unroll
            for (int mi = 0; mi < 2; ++mi)
#pragma unroll
                for (int ni = 0; ni < NI; ++ni)
                    acc[mi][ni] = __builtin_amdgcn_mfma_f32_16x16x32_bf16(af[mi], bf[ni], acc[mi][ni], 0, 0, 0);
        }
    }

    float p1a[NI], p2a[NI];
#pragma unroll
    for (int ni = 0; ni < NI; ++ni) { p1a[ni] = 0.f; p2a[ni] = 0.f; }
#pragma unroll
    for (int mi = 0; mi < 2; ++mi)
#pragma unroll
        for (int ni = 0; ni < NI; ++ni)
#pragma unroll
            for (int r = 0; r < 4; ++r) {
                float v = acc[mi][ni][r];
                int row = m0 + wm * 32 + mi * 16 + quad * 4 + r;
                int col = n0 + wc * (BN / 2) + ni * 16 + lr;
                Out[(size_t)row * OC + col] = f2bf(v);
                p1a[ni] += v; p2a[ni] += v * v;
            }
    __syncthreads();
#pragma unroll
    for (int ni = 0; ni < NI; ++ni) {
        atomicAdd(&sS1[wc * (BN / 2) + ni * 16 + lr], p1a[ni]);
        atomicAdd(&sS2[wc * (BN / 2) + ni * 16 + lr], p2a[ni]);
    }
    __syncthreads();
    if (tid < BN) {
        atomicAdd(&S1[n0 + tid], sS1[tid]);
        atomicAdd(&S2[n0 + tid], sS2[tid]);
    }
}

// ---------------- k_final: out = gelu( bn2(t2) + gelu(bn0(t0)) ) ----------------
__global__ __launch_bounds__(256) void k_final(const unsigned short* __restrict__ t0,
                                               const unsigned short* __restrict__ t2,
                                               const float* __restrict__ S1_0, const float* __restrict__ S2_0,
                                               const float* __restrict__ S1_2, const float* __restrict__ S2_2,
                                               const void* __restrict__ g0_, const void* __restrict__ bt0_,
                                               const void* __restrict__ g2_, const void* __restrict__ bt2_,
                                               const int* __restrict__ dflag,
                                               void* __restrict__ out_) {
    __shared__ float sA0[256], sC0[256], sA2[256], sC2[256];
    int tid = threadIdx.x;
    bool isf = (*dflag != 0);
    {
        float m0 = S1_0[tid] * (1.0f / (float)L);
        float v0_ = S2_0[tid] * (1.0f / (float)L) - m0 * m0;
        float m2 = S1_2[tid] * (1.0f / (float)L);
        float v2_ = S2_2[tid] * (1.0f / (float)L) - m2 * m2;
        float g0, b0, g2, b2;
        if (isf) {
            g0 = ((const float*)g0_)[tid]; b0 = ((const float*)bt0_)[tid];
            g2 = ((const float*)g2_)[tid]; b2 = ((const float*)bt2_)[tid];
        } else {
            g0 = bf2f(((const unsigned short*)g0_)[tid]); b0 = bf2f(((const unsigned short*)bt0_)[tid]);
            g2 = bf2f(((const unsigned short*)g2_)[tid]); b2 = bf2f(((const unsigned short*)bt2_)[tid]);
        }
        float a0 = g0 * rsqrtf(v0_ + BN_EPS);
        float a2 = g2 * rsqrtf(v2_ + BN_EPS);
        sA0[tid] = a0; sC0[tid] = b0 - m0 * a0;
        sA2[tid] = a2; sC2[tid] = b2 - m2 * a2;
    }
    __syncthreads();

    int idx = (blockIdx.x * 256 + tid) * 8;
    int col = idx & (OC - 1);
    union { uint4 v; unsigned short u[8]; } v0, v2;
    v0.v = *(const uint4*)(t0 + idx);
    v2.v = *(const uint4*)(t2 + idx);
    float r[8];
#pragma unroll
    for (int j = 0; j < 8; ++j) {
        float x = gelu_f(sA0[col + j] * bf2f(v0.u[j]) + sC0[col + j]);
        float y = sA2[col + j] * bf2f(v2.u[j]) + sC2[col + j];
        r[j] = gelu_f(x + y);
    }
    if (isf) {
        float* o = (float*)out_ + idx;
        float4 lo = {r[0], r[1], r[2], r[3]};
        float4 hi = {r[4], r[5], r[6], r[7]};
        *(float4*)o = lo;
        *(float4*)(o + 4) = hi;
    } else {
        union { uint4 v; unsigned short u[8]; } vo;
#pragma unroll
        for (int j = 0; j < 8; ++j) vo.u[j] = f2bf(r[j]);
        *(uint4*)((unsigned short*)out_ + idx) = vo.v;
    }
}

extern "C" void kernel_launch(void* const* d_in, const int* in_sizes, int n_in,
                              void* d_out, int out_size, void* d_ws, size_t ws_size,
                              hipStream_t stream) {
    const void* xyz1    = d_in[0];
    const void* xyz2    = d_in[1];
    const void* points1 = d_in[2];
    const void* points2 = d_in[3];
    const void* W_fuse  = d_in[4];
    const void* g_fuse  = d_in[6];
    const void* bt_fuse = d_in[7];
    const void* W1      = d_in[8];
    const void* g1      = d_in[10];
    const void* bt1     = d_in[11];
    const void* W2      = d_in[12];
    const void* g2      = d_in[14];
    const void* bt2     = d_in[15];

    char* ws = (char*)d_ws;
    unsigned short* t0 = (unsigned short*)ws;                 // 16.8 MB raw GEMM1 out
    unsigned short* t2 = (unsigned short*)(ws + 16777216);    // 16.8 MB raw GEMM3 out
    unsigned short* X  = (unsigned short*)d_out;              // 25.2 MB pre-swizzled (dead after GEMM1)
    unsigned short* t1 = (unsigned short*)d_out;              // 16.8 MB raw GEMM2 out (overwrites dead X)
    int*   nn_idx = (int*)(ws + 50331648);
    float* nn_w   = (float*)(ws + 50724864);
    float* stats  = (float*)(ws + 51118080);
    int*   dflag  = (int*)(ws + 51124224);
    unsigned short* Wbf = (unsigned short*)(ws + 51126272);   // Wf | W1 | W2, PRE-SWIZZLED bf16

    float *S1_0 = stats,        *S2_0 = stats + 256;
    float *S1_1 = stats + 512,  *S2_1 = stats + 768;
    float *S1_2 = stats + 1024, *S2_2 = stats + 1280;

    // 1: zero-stats + weight prep (pre-swizzled) + 3-NN
    k_front<<<1926, 256, 0, stream>>>(xyz1, xyz2, W_fuse, W1, W2, Wbf, stats, dflag, nn_idx, nn_w);
    // 2: materialize X (pre-swizzled bf16)
    k_interp<<<2048, 256, 0, stream>>>(points1, points2, nn_idx, nn_w, dflag, X);
    // 3: GEMM1 (X -> t0, stats0): K=384, BN=64, no act, A via glds
    k_pgemm<KIN, 64, false><<<(L / 64) * 4, 256, 0, stream>>>(
        X, Wbf, t0, S1_0, S2_0, nullptr, nullptr, nullptr, nullptr, dflag);
    // 4: GEMM2 (t0 -> t1, stats1): act fused into A-staging
    k_pgemm<OC, 128, true><<<(L / 64) * 2, 256, 0, stream>>>(
        t0, Wbf + 98304, t1, S1_1, S2_1, S1_0, S2_0, g_fuse, bt_fuse, dflag);
    // 5: GEMM3 (t1 -> t2, stats2): act fused into A-staging
    k_pgemm<OC, 128, true><<<(L / 64) * 2, 256, 0, stream>>>(
        t1, Wbf + 163840, t2, S1_2, S2_2, S1_1, S2_1, g1, bt1, dflag);
    // 6: final: out = gelu(bn2(t2) + gelu(bn0(t0)))
    k_final<<<L * OC / (256 * 8), 256, 0, stream>>>(t0, t2, S1_0, S2_0, S1_2, S2_2,
                                                    g_fuse, bt_fuse, g2, bt2, dflag, d_out);
}